// Round 1
// baseline (1854.511 us; speedup 1.0000x reference)
//
#include <hip/hip_runtime.h>
#include <hip/hip_bf16.h>
#include <math.h>

#define DIMD 512
#define NLAYER 4
#define PP 8
#define BBATCH 4
#define LBYTES 8192
#define LPATCH 1024
#define MROWS (BBATCH * LPATCH)   // 4096

// ---------------- generic f32 GEMM: C = act(A@W + bias) + res ----------------
#define BM 64
#define BN 64
#define BKK 32
#define LDSP 68   // padded row (floats), keeps 16B alignment, breaks bank stride

// ACT: 0 none, 1 tanh, 2 exact gelu
template<int ACT, bool BIAS, bool RES>
__global__ __launch_bounds__(256)
void gemm_kernel(const float* __restrict__ A, int lda, long aZ,
                 const float* __restrict__ W, int ldw, long wZ,
                 const float* __restrict__ bias,
                 const float* __restrict__ res, int ldr,
                 float* __restrict__ C, int ldc, long cZ,
                 int K)
{
    const int z = blockIdx.z;
    A += (long)z * aZ;
    W += (long)z * wZ;
    C += (long)z * cZ;

    __shared__ float As[BKK][LDSP];   // [k][row]  (A transposed in LDS)
    __shared__ float Bs[BKK][LDSP];   // [k][col]

    const int tid = threadIdx.x;
    const int tx = tid & 15;          // 0..15 -> 4 cols each
    const int ty = tid >> 4;          // 0..15 -> 4 rows each
    const int row0 = blockIdx.x * BM;
    const int col0 = blockIdx.y * BN;

    const int ar  = tid >> 2;         // 0..63 row in A tile
    const int ac4 = (tid & 3) * 4;    // k offset 0/4/8/12
    const int br  = tid >> 3;         // 0..31 k row in B tile
    const int bc4 = (tid & 7) * 4;    // col offset 0..28

    float acc[4][4] = {};

    for (int k0 = 0; k0 < K; k0 += BKK) {
        float4 a0 = *(const float4*)(A + (long)(row0 + ar) * lda + k0 + ac4);
        float4 a1 = *(const float4*)(A + (long)(row0 + ar) * lda + k0 + 16 + ac4);
        float4 b0 = *(const float4*)(W + (long)(k0 + br) * ldw + col0 + bc4);
        float4 b1 = *(const float4*)(W + (long)(k0 + br) * ldw + col0 + 32 + bc4);
        __syncthreads();   // previous iter consumers done
        As[ac4 + 0][ar] = a0.x;  As[ac4 + 1][ar] = a0.y;
        As[ac4 + 2][ar] = a0.z;  As[ac4 + 3][ar] = a0.w;
        As[ac4 + 16][ar] = a1.x; As[ac4 + 17][ar] = a1.y;
        As[ac4 + 18][ar] = a1.z; As[ac4 + 19][ar] = a1.w;
        *(float4*)&Bs[br][bc4]      = b0;
        *(float4*)&Bs[br][bc4 + 32] = b1;
        __syncthreads();
        #pragma unroll
        for (int kk = 0; kk < BKK; kk++) {
            float4 avv = *(const float4*)&As[kk][ty * 4];
            float4 bvv = *(const float4*)&Bs[kk][tx * 4];
            const float a_[4] = {avv.x, avv.y, avv.z, avv.w};
            const float b_[4] = {bvv.x, bvv.y, bvv.z, bvv.w};
            #pragma unroll
            for (int i = 0; i < 4; i++)
                #pragma unroll
                for (int j = 0; j < 4; j++)
                    acc[i][j] = fmaf(a_[i], b_[j], acc[i][j]);
        }
    }

    const int crow = row0 + ty * 4;
    const int ccol = col0 + tx * 4;
    float bv[4] = {0.f, 0.f, 0.f, 0.f};
    if (BIAS) {
        #pragma unroll
        for (int j = 0; j < 4; j++) bv[j] = bias[ccol + j];
    }
    #pragma unroll
    for (int i = 0; i < 4; i++) {
        float4 o;
        float* op = (float*)&o;
        const float* rr = RES ? (res + (long)(crow + i) * ldr + ccol) : nullptr;
        #pragma unroll
        for (int j = 0; j < 4; j++) {
            float v = acc[i][j] + bv[j];
            if (ACT == 1) v = tanhf(v);
            if (ACT == 2) v = 0.5f * v * (1.f + erff(v * 0.70710678118f));
            if (RES) v += rr[j];
            op[j] = v;
        }
        *(float4*)(C + (long)(crow + i) * ldc + ccol) = o;
    }
}

// ---------------- LayerNorm: one wave per row ----------------
__global__ __launch_bounds__(256)
void ln_kernel(const float* __restrict__ x, const float* __restrict__ g,
               const float* __restrict__ b, float* __restrict__ h)
{
    const int row = blockIdx.x * 4 + (threadIdx.x >> 6);
    const int lane = threadIdx.x & 63;
    const float* xr = x + (long)row * DIMD;
    float4 v0 = *(const float4*)(xr + lane * 8);
    float4 v1 = *(const float4*)(xr + lane * 8 + 4);
    float xv[8] = {v0.x, v0.y, v0.z, v0.w, v1.x, v1.y, v1.z, v1.w};
    float s = 0.f, q = 0.f;
    #pragma unroll
    for (int j = 0; j < 8; j++) { s += xv[j]; q += xv[j] * xv[j]; }
    #pragma unroll
    for (int off = 1; off < 64; off <<= 1) {
        s += __shfl_xor(s, off);
        q += __shfl_xor(q, off);
    }
    const float mean = s * (1.f / DIMD);
    const float var  = q * (1.f / DIMD) - mean * mean;
    const float rstd = rsqrtf(var + 1e-5f);
    float4 g0 = *(const float4*)(g + lane * 8);
    float4 g1 = *(const float4*)(g + lane * 8 + 4);
    float4 b0 = *(const float4*)(b + lane * 8);
    float4 b1 = *(const float4*)(b + lane * 8 + 4);
    float gv[8] = {g0.x, g0.y, g0.z, g0.w, g1.x, g1.y, g1.z, g1.w};
    float bb[8] = {b0.x, b0.y, b0.z, b0.w, b1.x, b1.y, b1.z, b1.w};
    float ov[8];
    #pragma unroll
    for (int j = 0; j < 8; j++) ov[j] = (xv[j] - mean) * rstd * gv[j] + bb[j];
    float* hr = h + (long)row * DIMD;
    *(float4*)(hr + lane * 8)     = make_float4(ov[0], ov[1], ov[2], ov[3]);
    *(float4*)(hr + lane * 8 + 4) = make_float4(ov[4], ov[5], ov[6], ov[7]);
}

// ---------------- fused embed+encode via precomputed table E ----------------
__global__ __launch_bounds__(128)
void embed_kernel(const int* __restrict__ bytes, const float* __restrict__ E,
                  const float* __restrict__ enc_b, float* __restrict__ x0)
{
    const int patch = blockIdx.x;           // b*1024 + lp
    __shared__ int by[PP];
    if (threadIdx.x < PP) by[threadIdx.x] = bytes[patch * PP + threadIdx.x];
    __syncthreads();
    const int o = threadIdx.x * 4;
    float4 acc = *(const float4*)(enc_b + o);
    #pragma unroll
    for (int p = 0; p < PP; p++) {
        float4 e = *(const float4*)(E + ((long)(p * 256 + by[p])) * DIMD + o);
        acc.x += e.x; acc.y += e.y; acc.z += e.z; acc.w += e.w;
    }
    *(float4*)(x0 + (long)patch * DIMD + o) = acc;
}

// ---------------- chunked cumsum scan ----------------
#define NCHUNK 32
#define CLEN   32   // LPATCH / NCHUNK

__global__ __launch_bounds__(512)
void scan_partial(const float* __restrict__ qkv, float* __restrict__ S)
{
    const int b = blockIdx.x >> 5, c = blockIdx.x & 31, d = threadIdx.x;
    const float* base = qkv + (long)(b * LPATCH + c * CLEN) * (3 * DIMD);
    float s = 0.f;
    for (int l = 0; l < CLEN; l++) {
        float k = base[l * 3 * DIMD + DIMD + d];
        float v = base[l * 3 * DIMD + 2 * DIMD + d];
        s = fmaf(k, v, s);
    }
    S[(b * NCHUNK + c) * DIMD + d] = s;
}

__global__ __launch_bounds__(512)
void scan_prefix(float* __restrict__ S)
{
    const int b = blockIdx.x, d = threadIdx.x;
    float run = 0.f;
    for (int c = 0; c < NCHUNK; c++) {
        float v = S[(b * NCHUNK + c) * DIMD + d];
        S[(b * NCHUNK + c) * DIMD + d] = run;
        run += v;
    }
}

__global__ __launch_bounds__(512)
void scan_apply(const float* __restrict__ qkv, const float* __restrict__ gate,
                const float* __restrict__ S, float* __restrict__ x)
{
    const int b = blockIdx.x >> 5, c = blockIdx.x & 31, d = threadIdx.x;
    float kv = S[(b * NCHUNK + c) * DIMD + d];
    const float* qb = qkv + (long)(b * LPATCH + c * CLEN) * (3 * DIMD);
    const float* gb = gate + (long)(b * LPATCH + c * CLEN) * DIMD;
    float* xb = x + (long)(b * LPATCH + c * CLEN) * DIMD;
    for (int l = 0; l < CLEN; l++) {
        float q = qb[l * 3 * DIMD + d];
        float k = qb[l * 3 * DIMD + DIMD + d];
        float v = qb[l * 3 * DIMD + 2 * DIMD + d];
        kv = fmaf(k, v, kv);
        float gp = gb[l * DIMD + d];
        float g = 1.f / (1.f + expf(-gp));
        xb[l * DIMD + d] += q * kv * g;
    }
}

// ---------------- fused bias for decoder+head ----------------
__global__ __launch_bounds__(256)
void fbias_kernel(const float* __restrict__ dec_b, const float* __restrict__ head_w,
                  const float* __restrict__ head_b, float* __restrict__ fb)
{
    const int col = blockIdx.x * 256 + threadIdx.x;   // p*256 + o
    const int o = col & 255;
    float s = head_b[o];
    for (int d = 0; d < DIMD; d++) s = fmaf(dec_b[d], head_w[d * 256 + o], s);
    fb[col] = s;
}

extern "C" void kernel_launch(void* const* d_in, const int* in_sizes, int n_in,
                              void* d_out, int out_size, void* d_ws, size_t ws_size,
                              hipStream_t stream)
{
    (void)in_sizes; (void)n_in; (void)out_size; (void)ws_size;

    const int*   bytes_in  = (const int*)d_in[0];
    const float* byte_emb  = (const float*)d_in[1];
    const float* enc_w     = (const float*)d_in[2];
    const float* enc_b     = (const float*)d_in[3];
    const float* hash_proj = (const float*)d_in[4];
    const float* qkv_w     = (const float*)d_in[5];
    const float* qkv_b     = (const float*)d_in[6];
    const float* gate_w    = (const float*)d_in[7];
    const float* gate_b    = (const float*)d_in[8];
    const float* ln1_g     = (const float*)d_in[9];
    const float* ln1_b     = (const float*)d_in[10];
    const float* mlp_w1    = (const float*)d_in[11];
    const float* mlp_b1    = (const float*)d_in[12];
    const float* mlp_w2    = (const float*)d_in[13];
    const float* mlp_b2    = (const float*)d_in[14];
    const float* ln2_g     = (const float*)d_in[15];
    const float* ln2_b     = (const float*)d_in[16];
    const float* dec_w     = (const float*)d_in[17];
    const float* dec_b     = (const float*)d_in[18];
    const float* head_w    = (const float*)d_in[19];
    const float* head_b    = (const float*)d_in[20];
    float* out = (float*)d_out;

    char* ws = (char*)d_ws;
    float* E    = (float*)(ws);                                  // 4 MB: [8][256][512]
    float* Wf   = (float*)(ws + (4u << 20));                     // 4 MB: [512][2048]
    float* fb   = (float*)(ws + (8u << 20));                     // 8 KB: [2048]
    float* x    = (float*)(ws + (8u << 20) + 65536);             // 8 MB
    float* h    = x    + (long)MROWS * DIMD;                     // 8 MB
    float* gate = h    + (long)MROWS * DIMD;                     // 8 MB
    float* S    = gate + (long)MROWS * DIMD;                     // 256 KB
    float* big  = S    + (long)BBATCH * NCHUNK * DIMD;           // 32 MB (qkv / mlp-hidden)
    float* x0   = big;                                           // alias: dead before qkv

    dim3 blk(256);

    // E[p] = byte_emb @ enc_w[p]
    gemm_kernel<0, false, false><<<dim3(256 / BM, DIMD / BN, PP), blk, 0, stream>>>(
        byte_emb, DIMD, 0L,
        enc_w, DIMD, (long)DIMD * DIMD,
        nullptr, nullptr, 0,
        E, DIMD, (long)256 * DIMD, DIMD);

    // Wf[:, p*256 : (p+1)*256] = dec_w[:, p, :] @ head_w
    gemm_kernel<0, false, false><<<dim3(DIMD / BM, 256 / BN, PP), blk, 0, stream>>>(
        dec_w, PP * DIMD, (long)DIMD,
        head_w, 256, 0L,
        nullptr, nullptr, 0,
        Wf, PP * 256, 256L, DIMD);

    fbias_kernel<<<dim3(8), dim3(256), 0, stream>>>(dec_b, head_w, head_b, fb);

    embed_kernel<<<dim3(MROWS), dim3(128), 0, stream>>>(bytes_in, E, enc_b, x0);

    // x = x0 + tanh(x0 @ hash_proj)
    gemm_kernel<1, false, true><<<dim3(MROWS / BM, DIMD / BN, 1), blk, 0, stream>>>(
        x0, DIMD, 0L, hash_proj, DIMD, 0L, nullptr, x0, DIMD, x, DIMD, 0L, DIMD);

    for (int i = 0; i < NLAYER; i++) {
        ln_kernel<<<dim3(MROWS / 4), blk, 0, stream>>>(x, ln1_g + i * DIMD, ln1_b + i * DIMD, h);
        gemm_kernel<0, true, false><<<dim3(MROWS / BM, (3 * DIMD) / BN, 1), blk, 0, stream>>>(
            h, DIMD, 0L, qkv_w + (long)i * DIMD * 3 * DIMD, 3 * DIMD, 0L,
            qkv_b + (long)i * 3 * DIMD, nullptr, 0, big, 3 * DIMD, 0L, DIMD);
        gemm_kernel<0, true, false><<<dim3(MROWS / BM, DIMD / BN, 1), blk, 0, stream>>>(
            h, DIMD, 0L, gate_w + (long)i * DIMD * DIMD, DIMD, 0L,
            gate_b + (long)i * DIMD, nullptr, 0, gate, DIMD, 0L, DIMD);
        scan_partial<<<dim3(BBATCH * NCHUNK), dim3(DIMD), 0, stream>>>(big, S);
        scan_prefix<<<dim3(BBATCH), dim3(DIMD), 0, stream>>>(S);
        scan_apply<<<dim3(BBATCH * NCHUNK), dim3(DIMD), 0, stream>>>(big, gate, S, x);
        ln_kernel<<<dim3(MROWS / 4), blk, 0, stream>>>(x, ln2_g + i * DIMD, ln2_b + i * DIMD, h);
        gemm_kernel<2, true, false><<<dim3(MROWS / BM, (4 * DIMD) / BN, 1), blk, 0, stream>>>(
            h, DIMD, 0L, mlp_w1 + (long)i * DIMD * 4 * DIMD, 4 * DIMD, 0L,
            mlp_b1 + (long)i * 4 * DIMD, nullptr, 0, big, 4 * DIMD, 0L, DIMD);
        gemm_kernel<0, true, true><<<dim3(MROWS / BM, DIMD / BN, 1), blk, 0, stream>>>(
            big, 4 * DIMD, 0L, mlp_w2 + (long)i * 4 * DIMD * DIMD, DIMD, 0L,
            mlp_b2 + (long)i * DIMD, x, DIMD, x, DIMD, 0L, 4 * DIMD);
    }

    // logits = x @ Wf + fb   -> [4096, 2048] == [B, L, 256]
    gemm_kernel<0, true, false><<<dim3(MROWS / BM, 2048 / BN, 1), blk, 0, stream>>>(
        x, DIMD, 0L, Wf, 2048, 0L, fb, nullptr, 0, out, 2048, 0L, DIMD);
}

// Round 2
// 562.625 us; speedup vs baseline: 3.2962x; 3.2962x over previous
//
#include <hip/hip_runtime.h>
#include <hip/hip_bf16.h>
#include <math.h>

#define DIMD 512
#define NLAYER 4
#define PP 8
#define BBATCH 4
#define LBYTES 8192
#define LPATCH 1024
#define MROWS (BBATCH * LPATCH)   // 4096

typedef __bf16 bf16x8 __attribute__((ext_vector_type(8)));
typedef float f32x4 __attribute__((ext_vector_type(4)));
typedef unsigned short u16x4 __attribute__((ext_vector_type(4)));
typedef unsigned short u16x8 __attribute__((ext_vector_type(8)));

__device__ __forceinline__ unsigned short f2bf(float f) {
    union { float f; unsigned u; } v; v.f = f;
    unsigned r = v.u + 0x7FFFu + ((v.u >> 16) & 1u);   // RNE
    return (unsigned short)(r >> 16);
}
__device__ __forceinline__ float bf2f(unsigned short u) {
    union { unsigned u; float f; } v; v.u = ((unsigned)u) << 16;
    return v.f;
}

__device__ __forceinline__ void glds16(const unsigned short* g, unsigned short* l) {
    __builtin_amdgcn_global_load_lds((__attribute__((address_space(1))) void*)g,
                                     (__attribute__((address_space(3))) void*)l,
                                     16, 0, 0);
}

// =======================================================================
// bf16 MFMA GEMM (NT): C[M,N] = act(A[M,K] @ Bt[N,K]^T + bias) (+res)
// m97 structure: 128-wide N tile, TM in {64,128}, BK=32, 4 waves, 2 barriers.
// =======================================================================
template<int TM, int ACT, bool BIAS, bool RES, bool OBF>
__global__ __launch_bounds__(256)
void mfma_gemm(const unsigned short* __restrict__ A, int lda,
               const unsigned short* __restrict__ Bt, int ldb,
               const float* __restrict__ bias,
               const float* __restrict__ res, int ldr,
               void* __restrict__ Cv, int ldc, int K)
{
    constexpr int M_REP = TM / 32;              // fragments per wave in M
    __shared__ unsigned short As[TM * 32];
    __shared__ unsigned short Bs[128 * 32];

    const int tid = threadIdx.x;
    const int w = tid >> 6, l = tid & 63;
    const int row0 = blockIdx.x * TM;
    const int col0 = blockIdx.y * 128;

    // ---- staging addresses (chunk c = 16B = 8 bf16; row = c>>2, k-off = (c&3)*8)
    const int cA = w * 64 + l;
    const unsigned short* gA0 = A + (size_t)(row0 + (cA >> 2)) * lda + (cA & 3) * 8;
    const unsigned short* gB0 = Bt + (size_t)(col0 + (cA >> 2)) * ldb + (cA & 3) * 8;
    const unsigned short* gB1 = Bt + (size_t)(col0 + 64 + (cA >> 2)) * ldb + (cA & 3) * 8;
    unsigned short* lA0 = &As[w * 512];
    unsigned short* lB0 = &Bs[w * 512];
    unsigned short* lB1 = &Bs[2048 + w * 512];
    const unsigned short* gA1 = nullptr;
    unsigned short* lA1 = nullptr;
    if constexpr (TM == 128) {
        gA1 = A + (size_t)(row0 + 64 + (cA >> 2)) * lda + (cA & 3) * 8;
        lA1 = &As[2048 + w * 512];
    }

    // ---- fragment addresses
    const int wr = (w >> 1) * (TM / 2);
    const int wc = (w & 1) * 64;
    const int lr = l & 15, lk = (l >> 4) * 8;
    const int aBase = (wr + lr) * 32 + lk;
    const int bBase = (wc + lr) * 32 + lk;

    f32x4 acc[M_REP][4] = {};

    for (int k0 = 0; k0 < K; k0 += 32) {
        glds16(gA0, lA0);  gA0 += 32;
        if constexpr (TM == 128) { glds16(gA1, lA1); gA1 += 32; }
        glds16(gB0, lB0);  gB0 += 32;
        glds16(gB1, lB1);  gB1 += 32;
        __syncthreads();                       // drains vmcnt: tile staged
        bf16x8 af[M_REP], bfr[4];
        #pragma unroll
        for (int m = 0; m < M_REP; m++)
            af[m] = *reinterpret_cast<const bf16x8*>(&As[aBase + m * 512]);
        #pragma unroll
        for (int n = 0; n < 4; n++)
            bfr[n] = *reinterpret_cast<const bf16x8*>(&Bs[bBase + n * 512]);
        #pragma unroll
        for (int m = 0; m < M_REP; m++)
            #pragma unroll
            for (int n = 0; n < 4; n++)
                acc[m][n] = __builtin_amdgcn_mfma_f32_16x16x32_bf16(
                    af[m], bfr[n], acc[m][n], 0, 0, 0);
        __syncthreads();                       // before next-iter overwrite
    }

    // ---- epilogue: C/D layout col=lane&15, row=(lane>>4)*4+reg
    const int r0 = row0 + wr + (l >> 4) * 4;
    const int c0 = col0 + wc + lr;
    float bv[4] = {0.f, 0.f, 0.f, 0.f};
    if (BIAS) {
        #pragma unroll
        for (int n = 0; n < 4; n++) bv[n] = bias[c0 + n * 16];
    }
    #pragma unroll
    for (int m = 0; m < M_REP; m++) {
        #pragma unroll
        for (int j = 0; j < 4; j++) {
            const int row = r0 + m * 16 + j;
            #pragma unroll
            for (int n = 0; n < 4; n++) {
                float v = acc[m][n][j];
                if (BIAS) v += bv[n];
                if (ACT == 1) v = tanhf(v);
                if (ACT == 2) v = 0.5f * v * (1.f + erff(v * 0.70710678118f));
                if (RES) v += res[(size_t)row * ldr + c0 + n * 16];
                if (OBF) ((unsigned short*)Cv)[(size_t)row * ldc + c0 + n * 16] = f2bf(v);
                else     ((float*)Cv)[(size_t)row * ldc + c0 + n * 16] = v;
            }
        }
    }
}

// ---------------- f32 SIMT GEMM (precomputes only) ----------------
#define BM 64
#define BN 64
#define BKK 32
#define LDSP 68

template<int ACT, bool BIAS, bool RES>
__global__ __launch_bounds__(256)
void gemm_kernel(const float* __restrict__ A, int lda, long aZ,
                 const float* __restrict__ W, int ldw, long wZ,
                 const float* __restrict__ bias,
                 const float* __restrict__ res, int ldr,
                 float* __restrict__ C, int ldc, long cZ, int K)
{
    const int z = blockIdx.z;
    A += (long)z * aZ; W += (long)z * wZ; C += (long)z * cZ;
    __shared__ float As[BKK][LDSP];
    __shared__ float Bs[BKK][LDSP];
    const int tid = threadIdx.x;
    const int tx = tid & 15, ty = tid >> 4;
    const int row0 = blockIdx.x * BM, col0 = blockIdx.y * BN;
    const int ar = tid >> 2, ac4 = (tid & 3) * 4;
    const int br = tid >> 3, bc4 = (tid & 7) * 4;
    float acc[4][4] = {};
    for (int k0 = 0; k0 < K; k0 += BKK) {
        float4 a0 = *(const float4*)(A + (long)(row0 + ar) * lda + k0 + ac4);
        float4 a1 = *(const float4*)(A + (long)(row0 + ar) * lda + k0 + 16 + ac4);
        float4 b0 = *(const float4*)(W + (long)(k0 + br) * ldw + col0 + bc4);
        float4 b1 = *(const float4*)(W + (long)(k0 + br) * ldw + col0 + 32 + bc4);
        __syncthreads();
        As[ac4 + 0][ar] = a0.x;  As[ac4 + 1][ar] = a0.y;
        As[ac4 + 2][ar] = a0.z;  As[ac4 + 3][ar] = a0.w;
        As[ac4 + 16][ar] = a1.x; As[ac4 + 17][ar] = a1.y;
        As[ac4 + 18][ar] = a1.z; As[ac4 + 19][ar] = a1.w;
        *(float4*)&Bs[br][bc4]      = b0;
        *(float4*)&Bs[br][bc4 + 32] = b1;
        __syncthreads();
        #pragma unroll
        for (int kk = 0; kk < BKK; kk++) {
            float4 avv = *(const float4*)&As[kk][ty * 4];
            float4 bvv = *(const float4*)&Bs[kk][tx * 4];
            const float a_[4] = {avv.x, avv.y, avv.z, avv.w};
            const float b_[4] = {bvv.x, bvv.y, bvv.z, bvv.w};
            #pragma unroll
            for (int i = 0; i < 4; i++)
                #pragma unroll
                for (int j = 0; j < 4; j++)
                    acc[i][j] = fmaf(a_[i], b_[j], acc[i][j]);
        }
    }
    const int crow = row0 + ty * 4, ccol = col0 + tx * 4;
    #pragma unroll
    for (int i = 0; i < 4; i++) {
        float4 o; float* op = (float*)&o;
        #pragma unroll
        for (int j = 0; j < 4; j++) op[j] = acc[i][j];
        *(float4*)(C + (long)(crow + i) * ldc + ccol) = o;
    }
}

// ---------------- transpose-pack: out_bf16[z][n][k] = in_f32[z][k][n] ----------------
__global__ __launch_bounds__(256)
void pack_t(const float* __restrict__ in, unsigned short* __restrict__ out,
            int K, int N)
{
    __shared__ float t[32][33];
    const int k0 = blockIdx.x * 32, n0 = blockIdx.y * 32;
    const size_t zo = (size_t)blockIdx.z * K * N;
    in += zo; out += zo;
    const int tx = threadIdx.x & 31, ty = threadIdx.x >> 5;   // ty 0..7
    #pragma unroll
    for (int i = 0; i < 4; i++)
        t[ty + i * 8][tx] = in[(size_t)(k0 + ty + i * 8) * N + n0 + tx];
    __syncthreads();
    #pragma unroll
    for (int i = 0; i < 4; i++)
        out[(size_t)(n0 + ty + i * 8) * K + k0 + tx] = f2bf(t[tx][ty + i * 8]);
}

// ---------------- LayerNorm: one wave per row, bf16 out ----------------
__global__ __launch_bounds__(256)
void ln_kernel(const float* __restrict__ x, const float* __restrict__ g,
               const float* __restrict__ b, unsigned short* __restrict__ h)
{
    const int row = blockIdx.x * 4 + (threadIdx.x >> 6);
    const int lane = threadIdx.x & 63;
    const float* xr = x + (long)row * DIMD;
    float4 v0 = *(const float4*)(xr + lane * 8);
    float4 v1 = *(const float4*)(xr + lane * 8 + 4);
    float xv[8] = {v0.x, v0.y, v0.z, v0.w, v1.x, v1.y, v1.z, v1.w};
    float s = 0.f, q = 0.f;
    #pragma unroll
    for (int j = 0; j < 8; j++) { s += xv[j]; q += xv[j] * xv[j]; }
    #pragma unroll
    for (int off = 1; off < 64; off <<= 1) {
        s += __shfl_xor(s, off);
        q += __shfl_xor(q, off);
    }
    const float mean = s * (1.f / DIMD);
    const float var  = q * (1.f / DIMD) - mean * mean;
    const float rstd = rsqrtf(var + 1e-5f);
    float4 g0 = *(const float4*)(g + lane * 8);
    float4 g1 = *(const float4*)(g + lane * 8 + 4);
    float4 b0 = *(const float4*)(b + lane * 8);
    float4 b1 = *(const float4*)(b + lane * 8 + 4);
    float gv[8] = {g0.x, g0.y, g0.z, g0.w, g1.x, g1.y, g1.z, g1.w};
    float bb[8] = {b0.x, b0.y, b0.z, b0.w, b1.x, b1.y, b1.z, b1.w};
    u16x8 o;
    #pragma unroll
    for (int j = 0; j < 8; j++) o[j] = f2bf((xv[j] - mean) * rstd * gv[j] + bb[j]);
    *reinterpret_cast<u16x8*>(h + (long)row * DIMD + lane * 8) = o;
}

// ---------------- fused embed+encode ----------------
__global__ __launch_bounds__(128)
void embed_kernel(const int* __restrict__ bytes, const float* __restrict__ E,
                  const float* __restrict__ enc_b, float* __restrict__ x0,
                  unsigned short* __restrict__ x0b)
{
    const int patch = blockIdx.x;
    __shared__ int by[PP];
    if (threadIdx.x < PP) by[threadIdx.x] = bytes[patch * PP + threadIdx.x];
    __syncthreads();
    const int o = threadIdx.x * 4;
    float4 acc = *(const float4*)(enc_b + o);
    #pragma unroll
    for (int p = 0; p < PP; p++) {
        float4 e = *(const float4*)(E + ((long)(p * 256 + by[p])) * DIMD + o);
        acc.x += e.x; acc.y += e.y; acc.z += e.z; acc.w += e.w;
    }
    *(float4*)(x0 + (long)patch * DIMD + o) = acc;
    u16x4 ob; ob[0] = f2bf(acc.x); ob[1] = f2bf(acc.y);
    ob[2] = f2bf(acc.z); ob[3] = f2bf(acc.w);
    *reinterpret_cast<u16x4*>(x0b + (long)patch * DIMD + o) = ob;
}

// ---------------- chunked cumsum scan (bf16 qkv/gate inputs) ----------------
#define NCHUNK 32
#define CLEN   32

__global__ __launch_bounds__(512)
void scan_partial(const unsigned short* __restrict__ qkv, float* __restrict__ S)
{
    const int b = blockIdx.x >> 5, c = blockIdx.x & 31, d = threadIdx.x;
    const unsigned short* base = qkv + (long)(b * LPATCH + c * CLEN) * (3 * DIMD);
    float s = 0.f;
    for (int l = 0; l < CLEN; l++) {
        float k = bf2f(base[l * 3 * DIMD + DIMD + d]);
        float v = bf2f(base[l * 3 * DIMD + 2 * DIMD + d]);
        s = fmaf(k, v, s);
    }
    S[(b * NCHUNK + c) * DIMD + d] = s;
}

__global__ __launch_bounds__(512)
void scan_prefix(float* __restrict__ S)
{
    const int b = blockIdx.x, d = threadIdx.x;
    float run = 0.f;
    for (int c = 0; c < NCHUNK; c++) {
        float v = S[(b * NCHUNK + c) * DIMD + d];
        S[(b * NCHUNK + c) * DIMD + d] = run;
        run += v;
    }
}

__global__ __launch_bounds__(512)
void scan_apply(const unsigned short* __restrict__ qkv,
                const unsigned short* __restrict__ gate,
                const float* __restrict__ S, float* __restrict__ x)
{
    const int b = blockIdx.x >> 5, c = blockIdx.x & 31, d = threadIdx.x;
    float kv = S[(b * NCHUNK + c) * DIMD + d];
    const unsigned short* qb = qkv + (long)(b * LPATCH + c * CLEN) * (3 * DIMD);
    const unsigned short* gb = gate + (long)(b * LPATCH + c * CLEN) * DIMD;
    float* xb = x + (long)(b * LPATCH + c * CLEN) * DIMD;
    for (int l = 0; l < CLEN; l++) {
        float q = bf2f(qb[l * 3 * DIMD + d]);
        float k = bf2f(qb[l * 3 * DIMD + DIMD + d]);
        float v = bf2f(qb[l * 3 * DIMD + 2 * DIMD + d]);
        kv = fmaf(k, v, kv);
        float gp = bf2f(gb[l * DIMD + d]);
        float g = 1.f / (1.f + expf(-gp));
        xb[l * DIMD + d] += q * kv * g;
    }
}

// ---------------- fused decoder+head bias ----------------
__global__ __launch_bounds__(256)
void fbias_kernel(const float* __restrict__ dec_b, const float* __restrict__ head_w,
                  const float* __restrict__ head_b, float* __restrict__ fb)
{
    const int col = blockIdx.x * 256 + threadIdx.x;
    const int o = col & 255;
    float s = head_b[o];
    for (int d = 0; d < DIMD; d++) s = fmaf(dec_b[d], head_w[d * 256 + o], s);
    fb[col] = s;
}

// ---------------- f32 -> bf16 cast ----------------
__global__ __launch_bounds__(256)
void cast_bf16(const float* __restrict__ in, unsigned short* __restrict__ out)
{
    const long i = (long)(blockIdx.x * 256 + threadIdx.x) * 8;
    float4 a = *(const float4*)(in + i);
    float4 b = *(const float4*)(in + i + 4);
    u16x8 o;
    o[0] = f2bf(a.x); o[1] = f2bf(a.y); o[2] = f2bf(a.z); o[3] = f2bf(a.w);
    o[4] = f2bf(b.x); o[5] = f2bf(b.y); o[6] = f2bf(b.z); o[7] = f2bf(b.w);
    *reinterpret_cast<u16x8*>(out + i) = o;
}

extern "C" void kernel_launch(void* const* d_in, const int* in_sizes, int n_in,
                              void* d_out, int out_size, void* d_ws, size_t ws_size,
                              hipStream_t stream)
{
    (void)in_sizes; (void)n_in; (void)out_size; (void)ws_size;

    const int*   bytes_in  = (const int*)d_in[0];
    const float* byte_emb  = (const float*)d_in[1];
    const float* enc_w     = (const float*)d_in[2];
    const float* enc_b     = (const float*)d_in[3];
    const float* hash_proj = (const float*)d_in[4];
    const float* qkv_w     = (const float*)d_in[5];
    const float* qkv_b     = (const float*)d_in[6];
    const float* gate_w    = (const float*)d_in[7];
    const float* gate_b    = (const float*)d_in[8];
    const float* ln1_g     = (const float*)d_in[9];
    const float* ln1_b     = (const float*)d_in[10];
    const float* mlp_w1    = (const float*)d_in[11];
    const float* mlp_b1    = (const float*)d_in[12];
    const float* mlp_w2    = (const float*)d_in[13];
    const float* mlp_b2    = (const float*)d_in[14];
    const float* ln2_g     = (const float*)d_in[15];
    const float* ln2_b     = (const float*)d_in[16];
    const float* dec_w     = (const float*)d_in[17];
    const float* dec_b     = (const float*)d_in[18];
    const float* head_w    = (const float*)d_in[19];
    const float* head_b    = (const float*)d_in[20];
    float* out = (float*)d_out;

    // ---- workspace layout (bytes) ----
    char* ws = (char*)d_ws;
    size_t o = 0;
    unsigned short* wqkvT = (unsigned short*)(ws + o); o += (size_t)4 * 1536 * 512 * 2;  // 6291456
    unsigned short* wgateT= (unsigned short*)(ws + o); o += (size_t)4 * 512 * 512 * 2;   // -> 8388608
    unsigned short* w1T   = (unsigned short*)(ws + o); o += (size_t)4 * 2048 * 512 * 2;  // -> 16777216
    unsigned short* w2T   = (unsigned short*)(ws + o); o += (size_t)4 * 512 * 2048 * 2;  // -> 25165824
    unsigned short* whashT= (unsigned short*)(ws + o); o += (size_t)512 * 512 * 2;       // -> 25690112
    unsigned short* wWfT  = (unsigned short*)(ws + o); o += (size_t)2048 * 512 * 2;      // -> 27787264
    float* fb             = (float*)(ws + o);          o += 2048 * 4;                    // -> 27795456
    float* x              = (float*)(ws + o);          o += (size_t)MROWS * DIMD * 4;    // -> 36184064
    unsigned short* h     = (unsigned short*)(ws + o); o += (size_t)MROWS * DIMD * 2;    // -> 40378368
    unsigned short* gateb = (unsigned short*)(ws + o); o += (size_t)MROWS * DIMD * 2;    // -> 44572672
    float* S              = (float*)(ws + o);          o += (size_t)BBATCH * NCHUNK * DIMD * 4; // -> 44834816
    char* big             = ws + o;                    // 16.78 MB shared region
    // inside big (time-multiplexed):
    float* Wff32          = (float*)big;                            // [512][2048] f32 (dies at pack)
    float* x0             = (float*)big;                            // [4096][512] f32
    float* E              = (float*)(big + 8388608);                // [2048][512] f32
    unsigned short* x0b   = (unsigned short*)(big + 12582912);      // [4096][512] bf16
    unsigned short* qkv   = (unsigned short*)big;                   // [4096][1536] bf16
    unsigned short* hid   = (unsigned short*)big;                   // [4096][2048] bf16
    unsigned short* xb    = h;                                      // h dead after last mlp1

    // ---- 1. weight transpose-packs (f32 [K][N] -> bf16 [N][K]) ----
    pack_t<<<dim3(16, 48, 4), 256, 0, stream>>>(qkv_w,  wqkvT, 512, 1536);
    pack_t<<<dim3(16, 16, 4), 256, 0, stream>>>(gate_w, wgateT, 512, 512);
    pack_t<<<dim3(16, 64, 4), 256, 0, stream>>>(mlp_w1, w1T, 512, 2048);
    pack_t<<<dim3(64, 16, 4), 256, 0, stream>>>(mlp_w2, w2T, 2048, 512);
    pack_t<<<dim3(16, 16, 1), 256, 0, stream>>>(hash_proj, whashT, 512, 512);

    // ---- 2. Wf = dec_w[:,p,:] @ head_w  (f32 SIMT), then pack to [2048][512] bf16
    gemm_kernel<0, false, false><<<dim3(DIMD / BM, 256 / BN, PP), 256, 0, stream>>>(
        dec_w, PP * DIMD, (long)DIMD, head_w, 256, 0L,
        nullptr, nullptr, 0, Wff32, PP * 256, 256L, DIMD);
    pack_t<<<dim3(16, 64, 1), 256, 0, stream>>>(Wff32, wWfT, 512, 2048);

    // ---- 3. E[p] = byte_emb @ enc_w[p]  (f32 SIMT)
    gemm_kernel<0, false, false><<<dim3(256 / BM, DIMD / BN, PP), 256, 0, stream>>>(
        byte_emb, DIMD, 0L, enc_w, DIMD, (long)DIMD * DIMD,
        nullptr, nullptr, 0, E, DIMD, (long)256 * DIMD, DIMD);

    fbias_kernel<<<dim3(8), dim3(256), 0, stream>>>(dec_b, head_w, head_b, fb);

    // ---- 4. embed (writes x0 f32 + x0b bf16)
    embed_kernel<<<dim3(MROWS), dim3(128), 0, stream>>>(bytes_in, E, enc_b, x0, x0b);

    // ---- 5. x = x0 + tanh(x0 @ hash_proj)
    mfma_gemm<64, 1, false, true, false><<<dim3(MROWS / 64, 4), 256, 0, stream>>>(
        x0b, DIMD, whashT, DIMD, nullptr, x0, DIMD, x, DIMD, DIMD);

    for (int i = 0; i < NLAYER; i++) {
        ln_kernel<<<dim3(MROWS / 4), 256, 0, stream>>>(x, ln1_g + i * DIMD, ln1_b + i * DIMD, h);
        mfma_gemm<128, 0, true, false, true><<<dim3(MROWS / 128, 12), 256, 0, stream>>>(
            h, DIMD, wqkvT + (size_t)i * 1536 * 512, DIMD,
            qkv_b + (size_t)i * 1536, nullptr, 0, qkv, 3 * DIMD, DIMD);
        mfma_gemm<64, 0, true, false, true><<<dim3(MROWS / 64, 4), 256, 0, stream>>>(
            h, DIMD, wgateT + (size_t)i * 512 * 512, DIMD,
            gate_b + (size_t)i * DIMD, nullptr, 0, gateb, DIMD, DIMD);
        scan_partial<<<dim3(BBATCH * NCHUNK), dim3(DIMD), 0, stream>>>(qkv, S);
        scan_prefix<<<dim3(BBATCH), dim3(DIMD), 0, stream>>>(S);
        scan_apply<<<dim3(BBATCH * NCHUNK), dim3(DIMD), 0, stream>>>(qkv, gateb, S, x);
        ln_kernel<<<dim3(MROWS / 4), 256, 0, stream>>>(x, ln2_g + i * DIMD, ln2_b + i * DIMD, h);
        mfma_gemm<128, 2, true, false, true><<<dim3(MROWS / 128, 16), 256, 0, stream>>>(
            h, DIMD, w1T + (size_t)i * 2048 * 512, DIMD,
            mlp_b1 + (size_t)i * 4 * DIMD, nullptr, 0, hid, 4 * DIMD, DIMD);
        mfma_gemm<64, 0, true, true, false><<<dim3(MROWS / 64, 4), 256, 0, stream>>>(
            hid, 4 * DIMD, w2T + (size_t)i * 512 * 2048, 4 * DIMD,
            mlp_b2 + (size_t)i * DIMD, x, DIMD, x, DIMD, 4 * DIMD);
    }

    // ---- 6. head: out = xb @ WfT^T + fb
    cast_bf16<<<dim3(MROWS * DIMD / (256 * 8)), 256, 0, stream>>>(x, xb);
    mfma_gemm<128, 0, true, false, false><<<dim3(MROWS / 128, 16), 256, 0, stream>>>(
        xb, DIMD, wWfT, DIMD, fb, nullptr, 0, out, 2048, DIMD);
}

// Round 3
// 483.393 us; speedup vs baseline: 3.8364x; 1.1639x over previous
//
#include <hip/hip_runtime.h>
#include <hip/hip_bf16.h>
#include <math.h>

#define DIMD 512
#define NLAYER 4
#define PP 8
#define BBATCH 4
#define LBYTES 8192
#define LPATCH 1024
#define MROWS (BBATCH * LPATCH)   // 4096

typedef __bf16 bf16x8 __attribute__((ext_vector_type(8)));
typedef float f32x4 __attribute__((ext_vector_type(4)));
typedef unsigned short u16x4 __attribute__((ext_vector_type(4)));
typedef unsigned short u16x8 __attribute__((ext_vector_type(8)));

__device__ __forceinline__ unsigned short f2bf(float f) {
    union { float f; unsigned u; } v; v.f = f;
    unsigned r = v.u + 0x7FFFu + ((v.u >> 16) & 1u);   // RNE
    return (unsigned short)(r >> 16);
}
__device__ __forceinline__ float bf2f(unsigned short u) {
    union { unsigned u; float f; } v; v.u = ((unsigned)u) << 16;
    return v.f;
}

__device__ __forceinline__ void glds16(const unsigned short* g, unsigned short* l) {
    __builtin_amdgcn_global_load_lds((__attribute__((address_space(1))) void*)g,
                                     (__attribute__((address_space(3))) void*)l,
                                     16, 0, 0);
}

// =======================================================================
// bf16 MFMA GEMM (NT): C[M,N] = act(A[M,K] @ Bt[N,K]^T + bias) (+res)
// z-batched: A += z*aZ, Bt += z*bZ, C += z*cZ (element strides).
// =======================================================================
template<int TM, int ACT, bool BIAS, bool RES, bool OBF>
__global__ __launch_bounds__(256)
void mfma_gemm(const unsigned short* __restrict__ A, int lda, long aZ,
               const unsigned short* __restrict__ Bt, int ldb, long bZ,
               const float* __restrict__ bias,
               const float* __restrict__ res, int ldr,
               void* __restrict__ Cv, int ldc, long cZ, int K)
{
    constexpr int M_REP = TM / 32;
    __shared__ unsigned short As[TM * 32];
    __shared__ unsigned short Bs[128 * 32];

    const int tid = threadIdx.x;
    const int w = tid >> 6, l = tid & 63;
    const int row0 = blockIdx.x * TM;
    const int col0 = blockIdx.y * 128;
    A  += (size_t)blockIdx.z * aZ;
    Bt += (size_t)blockIdx.z * bZ;
    unsigned short* Cb = (unsigned short*)Cv + (size_t)blockIdx.z * cZ;
    float*          Cf = (float*)Cv          + (size_t)blockIdx.z * cZ;

    const int cA = w * 64 + l;
    const unsigned short* gA0 = A + (size_t)(row0 + (cA >> 2)) * lda + (cA & 3) * 8;
    const unsigned short* gB0 = Bt + (size_t)(col0 + (cA >> 2)) * ldb + (cA & 3) * 8;
    const unsigned short* gB1 = Bt + (size_t)(col0 + 64 + (cA >> 2)) * ldb + (cA & 3) * 8;
    unsigned short* lA0 = &As[w * 512];
    unsigned short* lB0 = &Bs[w * 512];
    unsigned short* lB1 = &Bs[2048 + w * 512];
    const unsigned short* gA1 = nullptr;
    unsigned short* lA1 = nullptr;
    if constexpr (TM == 128) {
        gA1 = A + (size_t)(row0 + 64 + (cA >> 2)) * lda + (cA & 3) * 8;
        lA1 = &As[2048 + w * 512];
    }

    const int wr = (w >> 1) * (TM / 2);
    const int wc = (w & 1) * 64;
    const int lr = l & 15, lk = (l >> 4) * 8;
    const int aBase = (wr + lr) * 32 + lk;
    const int bBase = (wc + lr) * 32 + lk;

    f32x4 acc[M_REP][4] = {};

    for (int k0 = 0; k0 < K; k0 += 32) {
        glds16(gA0, lA0);  gA0 += 32;
        if constexpr (TM == 128) { glds16(gA1, lA1); gA1 += 32; }
        glds16(gB0, lB0);  gB0 += 32;
        glds16(gB1, lB1);  gB1 += 32;
        __syncthreads();
        bf16x8 af[M_REP], bfr[4];
        #pragma unroll
        for (int m = 0; m < M_REP; m++)
            af[m] = *reinterpret_cast<const bf16x8*>(&As[aBase + m * 512]);
        #pragma unroll
        for (int n = 0; n < 4; n++)
            bfr[n] = *reinterpret_cast<const bf16x8*>(&Bs[bBase + n * 512]);
        #pragma unroll
        for (int m = 0; m < M_REP; m++)
            #pragma unroll
            for (int n = 0; n < 4; n++)
                acc[m][n] = __builtin_amdgcn_mfma_f32_16x16x32_bf16(
                    af[m], bfr[n], acc[m][n], 0, 0, 0);
        __syncthreads();
    }

    const int r0 = row0 + wr + (l >> 4) * 4;
    const int c0 = col0 + wc + lr;
    float bv[4] = {0.f, 0.f, 0.f, 0.f};
    if (BIAS) {
        #pragma unroll
        for (int n = 0; n < 4; n++) bv[n] = bias[c0 + n * 16];
    }
    #pragma unroll
    for (int m = 0; m < M_REP; m++) {
        #pragma unroll
        for (int j = 0; j < 4; j++) {
            const int row = r0 + m * 16 + j;
            #pragma unroll
            for (int n = 0; n < 4; n++) {
                float v = acc[m][n][j];
                if (BIAS) v += bv[n];
                if (ACT == 1) v = tanhf(v);
                if (ACT == 2) v = 0.5f * v * (1.f + erff(v * 0.70710678118f));
                if (RES) v += res[(size_t)row * ldr + c0 + n * 16];
                if (OBF) Cb[(size_t)row * ldc + c0 + n * 16] = f2bf(v);
                else     Cf[(size_t)row * ldc + c0 + n * 16] = v;
            }
        }
    }
}

// ---- transpose-pack: out_bf16[n][k] = in_f32[k][n], z-batched w/ strides ----
__global__ __launch_bounds__(256)
void pack_t(const float* __restrict__ in, unsigned short* __restrict__ out,
            int K, int N, long inZ, long outZ)
{
    __shared__ float t[32][33];
    const int k0 = blockIdx.x * 32, n0 = blockIdx.y * 32;
    in  += (size_t)blockIdx.z * inZ;
    out += (size_t)blockIdx.z * outZ;
    const int tx = threadIdx.x & 31, ty = threadIdx.x >> 5;
    #pragma unroll
    for (int i = 0; i < 4; i++)
        t[ty + i * 8][tx] = in[(size_t)(k0 + ty + i * 8) * N + n0 + tx];
    __syncthreads();
    #pragma unroll
    for (int i = 0; i < 4; i++)
        out[(size_t)(n0 + ty + i * 8) * K + k0 + tx] = f2bf(t[tx][ty + i * 8]);
}

// ---- LayerNorm: one wave per row, bf16 out ----
__global__ __launch_bounds__(256)
void ln_kernel(const float* __restrict__ x, const float* __restrict__ g,
               const float* __restrict__ b, unsigned short* __restrict__ h)
{
    const int row = blockIdx.x * 4 + (threadIdx.x >> 6);
    const int lane = threadIdx.x & 63;
    const float* xr = x + (long)row * DIMD;
    float4 v0 = *(const float4*)(xr + lane * 8);
    float4 v1 = *(const float4*)(xr + lane * 8 + 4);
    float xv[8] = {v0.x, v0.y, v0.z, v0.w, v1.x, v1.y, v1.z, v1.w};
    float s = 0.f, q = 0.f;
    #pragma unroll
    for (int j = 0; j < 8; j++) { s += xv[j]; q += xv[j] * xv[j]; }
    #pragma unroll
    for (int off = 1; off < 64; off <<= 1) {
        s += __shfl_xor(s, off);
        q += __shfl_xor(q, off);
    }
    const float mean = s * (1.f / DIMD);
    const float var  = q * (1.f / DIMD) - mean * mean;
    const float rstd = rsqrtf(var + 1e-5f);
    float4 g0 = *(const float4*)(g + lane * 8);
    float4 g1 = *(const float4*)(g + lane * 8 + 4);
    float4 b0 = *(const float4*)(b + lane * 8);
    float4 b1 = *(const float4*)(b + lane * 8 + 4);
    float gv[8] = {g0.x, g0.y, g0.z, g0.w, g1.x, g1.y, g1.z, g1.w};
    float bb[8] = {b0.x, b0.y, b0.z, b0.w, b1.x, b1.y, b1.z, b1.w};
    u16x8 o;
    #pragma unroll
    for (int j = 0; j < 8; j++) o[j] = f2bf((xv[j] - mean) * rstd * gv[j] + bb[j]);
    *reinterpret_cast<u16x8*>(h + (long)row * DIMD + lane * 8) = o;
}

// ---- fused embed+encode ----
__global__ __launch_bounds__(128)
void embed_kernel(const int* __restrict__ bytes, const float* __restrict__ E,
                  const float* __restrict__ enc_b, float* __restrict__ x0,
                  unsigned short* __restrict__ x0b)
{
    const int patch = blockIdx.x;
    __shared__ int by[PP];
    if (threadIdx.x < PP) by[threadIdx.x] = bytes[patch * PP + threadIdx.x];
    __syncthreads();
    const int o = threadIdx.x * 4;
    float4 acc = *(const float4*)(enc_b + o);
    #pragma unroll
    for (int p = 0; p < PP; p++) {
        float4 e = *(const float4*)(E + ((long)(p * 256 + by[p])) * DIMD + o);
        acc.x += e.x; acc.y += e.y; acc.z += e.z; acc.w += e.w;
    }
    *(float4*)(x0 + (long)patch * DIMD + o) = acc;
    u16x4 ob; ob[0] = f2bf(acc.x); ob[1] = f2bf(acc.y);
    ob[2] = f2bf(acc.z); ob[3] = f2bf(acc.w);
    *reinterpret_cast<u16x4*>(x0b + (long)patch * DIMD + o) = ob;
}

// ---- chunked cumsum scan over combined qkv|gate buffer [4096][2048] ----
#define NCHUNK 64
#define CLEN   16
#define QGS    (4 * DIMD)   // 2048

__global__ __launch_bounds__(512)
void scan_partial(const unsigned short* __restrict__ qg, float* __restrict__ S)
{
    const int b = blockIdx.x >> 6, c = blockIdx.x & 63, d = threadIdx.x;
    const unsigned short* base = qg + (long)(b * LPATCH + c * CLEN) * QGS;
    float s = 0.f;
    for (int l = 0; l < CLEN; l++) {
        float k = bf2f(base[l * QGS + DIMD + d]);
        float v = bf2f(base[l * QGS + 2 * DIMD + d]);
        s = fmaf(k, v, s);
    }
    S[(b * NCHUNK + c) * DIMD + d] = s;
}

__global__ __launch_bounds__(512)
void scan_prefix(float* __restrict__ S)
{
    const int b = blockIdx.x, d = threadIdx.x;
    float run = 0.f;
    for (int c = 0; c < NCHUNK; c++) {
        float v = S[(b * NCHUNK + c) * DIMD + d];
        S[(b * NCHUNK + c) * DIMD + d] = run;
        run += v;
    }
}

__global__ __launch_bounds__(512)
void scan_apply(const unsigned short* __restrict__ qg,
                const float* __restrict__ S, float* __restrict__ x)
{
    const int b = blockIdx.x >> 6, c = blockIdx.x & 63, d = threadIdx.x;
    float kv = S[(b * NCHUNK + c) * DIMD + d];
    const unsigned short* qb = qg + (long)(b * LPATCH + c * CLEN) * QGS;
    float* xb = x + (long)(b * LPATCH + c * CLEN) * DIMD;
    for (int l = 0; l < CLEN; l++) {
        float q = bf2f(qb[l * QGS + d]);
        float k = bf2f(qb[l * QGS + DIMD + d]);
        float v = bf2f(qb[l * QGS + 2 * DIMD + d]);
        float gp = bf2f(qb[l * QGS + 3 * DIMD + d]);
        kv = fmaf(k, v, kv);
        float g = 1.f / (1.f + expf(-gp));
        xb[l * DIMD + d] += q * kv * g;
    }
}

// ---- concat qkv_b|gate_b per layer -> cbias[4][2048] ----
__global__ __launch_bounds__(256)
void catbias(const float* __restrict__ qb, const float* __restrict__ gb,
             float* __restrict__ cb)
{
    const int i = blockIdx.x >> 3;
    const int n = (blockIdx.x & 7) * 256 + threadIdx.x;
    cb[i * 2048 + n] = (n < 1536) ? qb[i * 1536 + n] : gb[i * 512 + n - 1536];
}

// ---- fused decoder+head bias: fb[p*256+o] = head_b[o] + dec_b . head_w[:,o] ----
__global__ __launch_bounds__(256)
void fbias2(const unsigned short* __restrict__ hwT, const float* __restrict__ dec_b,
            const float* __restrict__ head_b, float* __restrict__ fb)
{
    const int w = threadIdx.x >> 6, l = threadIdx.x & 63;
    const int o = blockIdx.x * 4 + w;
    u16x8 hv = *reinterpret_cast<const u16x8*>(hwT + (size_t)o * DIMD + l * 8);
    float4 d0 = *(const float4*)(dec_b + l * 8);
    float4 d1 = *(const float4*)(dec_b + l * 8 + 4);
    float dd[8] = {d0.x, d0.y, d0.z, d0.w, d1.x, d1.y, d1.z, d1.w};
    float s = 0.f;
    #pragma unroll
    for (int j = 0; j < 8; j++) s += bf2f(hv[j]) * dd[j];
    #pragma unroll
    for (int off = 1; off < 64; off <<= 1) s += __shfl_xor(s, off);
    if (l == 0) {
        float v = s + head_b[o];
        #pragma unroll
        for (int p = 0; p < PP; p++) fb[p * 256 + o] = v;
    }
}

// ---- f32 -> bf16 cast (8 elems/thread) ----
__global__ __launch_bounds__(256)
void cast_bf16(const float* __restrict__ in, unsigned short* __restrict__ out)
{
    const long i = (long)(blockIdx.x * 256 + threadIdx.x) * 8;
    float4 a = *(const float4*)(in + i);
    float4 b = *(const float4*)(in + i + 4);
    u16x8 o;
    o[0] = f2bf(a.x); o[1] = f2bf(a.y); o[2] = f2bf(a.z); o[3] = f2bf(a.w);
    o[4] = f2bf(b.x); o[5] = f2bf(b.y); o[6] = f2bf(b.z); o[7] = f2bf(b.w);
    *reinterpret_cast<u16x8*>(out + i) = o;
}

extern "C" void kernel_launch(void* const* d_in, const int* in_sizes, int n_in,
                              void* d_out, int out_size, void* d_ws, size_t ws_size,
                              hipStream_t stream)
{
    (void)in_sizes; (void)n_in; (void)out_size; (void)ws_size;

    const int*   bytes_in  = (const int*)d_in[0];
    const float* byte_emb  = (const float*)d_in[1];
    const float* enc_w     = (const float*)d_in[2];
    const float* enc_b     = (const float*)d_in[3];
    const float* hash_proj = (const float*)d_in[4];
    const float* qkv_w     = (const float*)d_in[5];
    const float* qkv_b     = (const float*)d_in[6];
    const float* gate_w    = (const float*)d_in[7];
    const float* gate_b    = (const float*)d_in[8];
    const float* ln1_g     = (const float*)d_in[9];
    const float* ln1_b     = (const float*)d_in[10];
    const float* mlp_w1    = (const float*)d_in[11];
    const float* mlp_b1    = (const float*)d_in[12];
    const float* mlp_w2    = (const float*)d_in[13];
    const float* mlp_b2    = (const float*)d_in[14];
    const float* ln2_g     = (const float*)d_in[15];
    const float* ln2_b     = (const float*)d_in[16];
    const float* dec_w     = (const float*)d_in[17];
    const float* dec_b     = (const float*)d_in[18];
    const float* head_w    = (const float*)d_in[19];
    const float* head_b    = (const float*)d_in[20];
    float* out = (float*)d_out;

    // ---- workspace layout ----
    char* ws = (char*)d_ws;
    size_t o = 0;
    auto alloc = [&](size_t bytes) { char* p = ws + o; o += (bytes + 255) & ~(size_t)255; return p; };
    unsigned short* wcat   = (unsigned short*)alloc((size_t)4 * 2048 * 512 * 2);
    unsigned short* w1T    = (unsigned short*)alloc((size_t)4 * 2048 * 512 * 2);
    unsigned short* w2T    = (unsigned short*)alloc((size_t)4 * 512 * 2048 * 2);
    unsigned short* whashT = (unsigned short*)alloc((size_t)512 * 512 * 2);
    unsigned short* wWfT   = (unsigned short*)alloc((size_t)2048 * 512 * 2);
    unsigned short* encT   = (unsigned short*)alloc((size_t)8 * 512 * 512 * 2);
    unsigned short* hwT    = (unsigned short*)alloc((size_t)256 * 512 * 2);
    unsigned short* decb   = (unsigned short*)alloc((size_t)512 * 8 * 512 * 2);
    unsigned short* embB   = (unsigned short*)alloc((size_t)256 * 512 * 2);
    float* cbias           = (float*)alloc((size_t)4 * 2048 * 4);
    float* fb              = (float*)alloc(2048 * 4);
    float* E               = (float*)alloc((size_t)8 * 256 * 512 * 4);
    float* x               = (float*)alloc((size_t)MROWS * DIMD * 4);
    float* x0              = (float*)alloc((size_t)MROWS * DIMD * 4);
    unsigned short* x0b    = (unsigned short*)alloc((size_t)MROWS * DIMD * 2);
    unsigned short* h      = (unsigned short*)alloc((size_t)MROWS * DIMD * 2);
    unsigned short* xb     = (unsigned short*)alloc((size_t)MROWS * DIMD * 2);
    float* S               = (float*)alloc((size_t)BBATCH * NCHUNK * DIMD * 4);
    unsigned short* qg     = (unsigned short*)alloc((size_t)MROWS * 2048 * 2);
    unsigned short* hid    = (unsigned short*)alloc((size_t)MROWS * 2048 * 2);

    // ---- weight packs ----
    pack_t<<<dim3(16, 48, 4), 256, 0, stream>>>(qkv_w, wcat, 512, 1536,
        (long)512 * 1536, (long)2048 * 512);
    pack_t<<<dim3(16, 16, 4), 256, 0, stream>>>(gate_w, wcat + (size_t)1536 * 512, 512, 512,
        (long)512 * 512, (long)2048 * 512);
    pack_t<<<dim3(16, 64, 4), 256, 0, stream>>>(mlp_w1, w1T, 512, 2048,
        (long)512 * 2048, (long)2048 * 512);
    pack_t<<<dim3(64, 16, 4), 256, 0, stream>>>(mlp_w2, w2T, 2048, 512,
        (long)2048 * 512, (long)512 * 2048);
    pack_t<<<dim3(16, 16, 1), 256, 0, stream>>>(hash_proj, whashT, 512, 512, 0, 0);
    pack_t<<<dim3(16, 8, 1), 256, 0, stream>>>(head_w, hwT, 512, 256, 0, 0);
    pack_t<<<dim3(16, 16, 8), 256, 0, stream>>>(enc_w, encT, 512, 512,
        (long)512 * 512, (long)512 * 512);
    cast_bf16<<<dim3(1024), 256, 0, stream>>>(dec_w, decb);     // [512][8][512]
    cast_bf16<<<dim3(64), 256, 0, stream>>>(byte_emb, embB);    // [256][512]
    catbias<<<dim3(32), 256, 0, stream>>>(qkv_b, gate_b, cbias);

    // ---- WfT[p*256+o][d] = sum_c head_wT[o][c] * dec_w[d][p][c]  (bf16 out) ----
    mfma_gemm<64, 0, false, false, true><<<dim3(4, 4, 8), 256, 0, stream>>>(
        hwT, 512, 0L, decb, PP * 512, 512L,
        nullptr, nullptr, 0, wWfT, 512, (long)256 * 512, 512);
    fbias2<<<dim3(64), 256, 0, stream>>>(hwT, dec_b, head_b, fb);

    // ---- E[p] = byte_emb @ enc_w[p]  (f32 out) ----
    mfma_gemm<64, 0, false, false, false><<<dim3(4, 4, 8), 256, 0, stream>>>(
        embB, 512, 0L, encT, 512, (long)512 * 512,
        nullptr, nullptr, 0, E, 512, (long)256 * 512, 512);

    embed_kernel<<<dim3(MROWS), dim3(128), 0, stream>>>(bytes_in, E, enc_b, x0, x0b);

    // ---- x = x0 + tanh(x0 @ hash_proj) ----
    mfma_gemm<64, 1, false, true, false><<<dim3(MROWS / 64, 4, 1), 256, 0, stream>>>(
        x0b, DIMD, 0L, whashT, DIMD, 0L, nullptr, x0, DIMD, x, DIMD, 0L, DIMD);

    for (int i = 0; i < NLAYER; i++) {
        ln_kernel<<<dim3(MROWS / 4), 256, 0, stream>>>(x, ln1_g + i * DIMD, ln1_b + i * DIMD, h);
        // fused qkv|gate: N = 2048
        mfma_gemm<128, 0, true, false, true><<<dim3(MROWS / 128, 16, 1), 256, 0, stream>>>(
            h, DIMD, 0L, wcat + (size_t)i * 2048 * 512, DIMD, 0L,
            cbias + (size_t)i * 2048, nullptr, 0, qg, 2048, 0L, DIMD);
        scan_partial<<<dim3(BBATCH * NCHUNK), dim3(DIMD), 0, stream>>>(qg, S);
        scan_prefix<<<dim3(BBATCH), dim3(DIMD), 0, stream>>>(S);
        scan_apply<<<dim3(BBATCH * NCHUNK), dim3(DIMD), 0, stream>>>(qg, S, x);
        ln_kernel<<<dim3(MROWS / 4), 256, 0, stream>>>(x, ln2_g + i * DIMD, ln2_b + i * DIMD, h);
        mfma_gemm<128, 2, true, false, true><<<dim3(MROWS / 128, 16, 1), 256, 0, stream>>>(
            h, DIMD, 0L, w1T + (size_t)i * 2048 * 512, DIMD, 0L,
            mlp_b1 + (size_t)i * 2048, nullptr, 0, hid, 2048, 0L, DIMD);
        if (i < NLAYER - 1) {
            mfma_gemm<64, 0, true, true, false><<<dim3(MROWS / 64, 4, 1), 256, 0, stream>>>(
                hid, 2048, 0L, w2T + (size_t)i * 512 * 2048, 2048, 0L,
                mlp_b2 + (size_t)i * DIMD, x, DIMD, x, DIMD, 0L, 2048);
        } else {
            // last layer: write bf16 xb directly (head input); x no longer needed
            mfma_gemm<64, 0, true, true, true><<<dim3(MROWS / 64, 4, 1), 256, 0, stream>>>(
                hid, 2048, 0L, w2T + (size_t)i * 512 * 2048, 2048, 0L,
                mlp_b2 + (size_t)i * DIMD, x, DIMD, xb, DIMD, 0L, 2048);
        }
    }

    // ---- head: out = xb @ WfT^T + fb ----
    mfma_gemm<128, 0, true, false, false><<<dim3(MROWS / 128, 16, 1), 256, 0, stream>>>(
        xb, DIMD, 0L, wWfT, DIMD, 0L, fb, nullptr, 0, out, 2048, 0L, DIMD);
}